// Round 3
// baseline (489.251 us; speedup 1.0000x reference)
//
#include <hip/hip_runtime.h>
#include <hip/hip_bf16.h>
#include <stdint.h>

typedef __bf16 bf16x8 __attribute__((ext_vector_type(8)));
typedef float f32x4 __attribute__((ext_vector_type(4)));
typedef unsigned short u16;
typedef unsigned int u32;

#define DEVI __device__ __forceinline__

DEVI u16 f2b(float f){ __bf16 h = (__bf16)f; return __builtin_bit_cast(u16, h); }
DEVI float b2f(u16 u){ return (float)__builtin_bit_cast(__bf16, u); }

constexpr int BSZ = 2, SEQ = 2048, DIM = 2048, NH = 16, HD = 128;

#if defined(__has_builtin)
#if __has_builtin(__builtin_amdgcn_global_load_lds)
#define HAVE_ASYNC_LDS 1
#endif
#endif

DEVI void cp16(void* lds, const void* g){
#ifdef HAVE_ASYNC_LDS
  auto gp = (const __attribute__((address_space(1))) u32*)(uintptr_t)g;
  auto lp = (__attribute__((address_space(3))) u32*)(uintptr_t)lds;
  __builtin_amdgcn_global_load_lds(gp, lp, 16, 0, 0);
#else
  *(uint4*)lds = *(const uint4*)g;
#endif
}

// ---------------------------------------------------------------- convert
__global__ __launch_bounds__(256) void k_convert(
    const float* __restrict__ x, const float* __restrict__ wq,
    const float* __restrict__ wk, const float* __restrict__ wv,
    const float* __restrict__ wo,
    u16* __restrict__ xb, u16* __restrict__ wqkv, u16* __restrict__ wob)
{
  int e = (blockIdx.x * 256 + threadIdx.x) * 4;
  float4 v; u16* dp;
  if (e < 8388608){
    v = *(const float4*)&x[e]; dp = &xb[e];
  } else if (e < 20971520){
    int o = e - 8388608; int sec = o >> 22; int oo = o & 4194303;
    const float* w = (sec == 0) ? wq : ((sec == 1) ? wk : wv);
    v = *(const float4*)&w[oo]; dp = &wqkv[o];
  } else {
    int o = e - 20971520;
    v = *(const float4*)&wo[o]; dp = &wob[o];
  }
  ushort4 r; r.x = f2b(v.x); r.y = f2b(v.y); r.z = f2b(v.z); r.w = f2b(v.w);
  *(ushort4*)dp = r;
}

// ---------------------------------------------------------------- gemm QKV (+fused RoPE epilogue)
// C[m,n] = sum_k A[m,k]*W[n,k]. Each 128-col block lies in exactly one (sec,h);
// epilogue round-trips acc through LDS, applies RoPE (Q also pre-scaled by
// 1/sqrt(HD)*log2e), stores fully-coalesced b128.
__global__ __launch_bounds__(256) void k_gemm_qkv(
    const u16* __restrict__ A, const u16* __restrict__ W,
    const float* __restrict__ fc, const float* __restrict__ fs,
    u16* __restrict__ Qd, u16* __restrict__ Kd, u16* __restrict__ Vd)
{
  __shared__ u16 As[128*32];
  __shared__ u16 Bs[128*32];
  __shared__ u16 Cs[128*136];
  const int t = threadIdx.x;
  const int lane = t & 63;
  const int l15 = lane & 15, quad = lane >> 4;
  const int wave = t >> 6;
  const int wr = (wave >> 1) * 64, wc = (wave & 1) * 64;
  const int tm = blockIdx.y * 128, tn = blockIdx.x * 128;
  const int arow = t >> 2, acol = (t & 3) * 8;

  f32x4 acc[4][4] = {};
  for (int k0 = 0; k0 < DIM; k0 += 32){
    __syncthreads();
    #pragma unroll
    for (int is = 0; is < 2; ++is){
      int row = is*64 + arow;
      cp16(&As[is*2048 + t*8], &A[(size_t)(tm + row)*DIM + k0 + acol]);
      cp16(&Bs[is*2048 + t*8], &W[(size_t)(tn + row)*DIM + k0 + acol]);
    }
    __syncthreads();
    bf16x8 af[4], bfr[4];
    #pragma unroll
    for (int i = 0; i < 4; ++i){
      af[i]  = *(const bf16x8*)&As[(wr + i*16 + l15)*32 + quad*8];
      bfr[i] = *(const bf16x8*)&Bs[(wc + i*16 + l15)*32 + quad*8];
    }
    #pragma unroll
    for (int mt = 0; mt < 4; ++mt)
      #pragma unroll
      for (int nt = 0; nt < 4; ++nt)
        acc[mt][nt] = __builtin_amdgcn_mfma_f32_16x16x32_bf16(af[mt], bfr[nt], acc[mt][nt], 0, 0, 0);
  }
  // acc -> LDS (bf16, stride 136)
  #pragma unroll
  for (int mt = 0; mt < 4; ++mt)
    #pragma unroll
    for (int nt = 0; nt < 4; ++nt)
      #pragma unroll
      for (int r = 0; r < 4; ++r)
        Cs[(wr + mt*16 + quad*4 + r)*136 + wc + nt*16 + l15] = f2b(acc[mt][nt][r]);
  __syncthreads();

  const int sec = tn >> 11;                 // 0=Q 1=K 2=V (block-uniform)
  const int hh = (tn & 2047) >> 7;          // head (block-uniform)
  u16* dst = (sec == 0) ? Qd : ((sec == 1) ? Kd : Vd);
  const float qs = (sec == 0) ? (0.08838834764831845f * 1.4426950408889634f) : 1.0f;
  const int col0 = (t & 15) * 8;
  #pragma unroll
  for (int jj = 0; jj < 8; ++jj){
    int row = (t >> 4) + jj*16;
    int m = tm + row;
    int b = m >> 11, s = m & 2047;
    uint4 cv = *(const uint4*)&Cs[row*136 + col0];
    const u16* cp = (const u16*)&cv;
    u16 op[8];
    if (sec < 2){
      float4 c4 = *(const float4*)&fc[(size_t)s*64 + (col0 >> 1)];
      float4 s4 = *(const float4*)&fs[(size_t)s*64 + (col0 >> 1)];
      float cc[4] = {c4.x*qs, c4.y*qs, c4.z*qs, c4.w*qs};
      float ss[4] = {s4.x*qs, s4.y*qs, s4.z*qs, s4.w*qs};
      #pragma unroll
      for (int p = 0; p < 4; ++p){
        float a = b2f(cp[2*p]), bb = b2f(cp[2*p+1]);
        op[2*p]   = f2b(a*cc[p] - bb*ss[p]);
        op[2*p+1] = f2b(a*ss[p] + bb*cc[p]);
      }
    } else {
      #pragma unroll
      for (int p = 0; p < 8; ++p) op[p] = cp[p];
    }
    *(uint4*)&dst[((size_t)(b*NH + hh)*SEQ + s)*HD + col0] = *(const uint4*)op;
  }
}

// ---------------------------------------------------------------- V transpose
__global__ __launch_bounds__(256) void k_vtrans(
    const u16* __restrict__ V, u16* __restrict__ Vt)
{
  __shared__ u16 ts[64*72];
  const int t = threadIdx.x;
  const int st = blockIdx.x, dt = blockIdx.y, bh = blockIdx.z;
  const size_t base  = (size_t)bh * SEQ * HD;
  const size_t baseT = (size_t)bh * HD * SEQ;
  #pragma unroll
  for (int i = 0; i < 2; ++i){
    int s = i*32 + (t>>3), c = t&7;
    *(uint4*)&ts[s*72 + c*8] = *(const uint4*)&V[base + (size_t)(st*64 + s)*HD + dt*64 + c*8];
  }
  __syncthreads();
  #pragma unroll
  for (int i = 0; i < 2; ++i){
    int d = i*32 + (t>>3), sc = t&7;
    u16 tmp[8];
    #pragma unroll
    for (int j = 0; j < 8; ++j) tmp[j] = ts[(sc*8 + j)*72 + d];
    *(uint4*)&Vt[baseT + (size_t)(dt*64 + d)*SEQ + st*64 + sc*8] = *(const uint4*)tmp;
  }
}

// ---------------------------------------------------------------- flash attention (split-K = 2)
// grid (16, NH, B): x = j*2+split, j in [0,8). Block handles q-tiles {j, 15-j}
// (34 k-tiles total), split s takes global tile indices [17s, 17s+17).
// Writes unnormalized partial O (bf16) + per-row m,l (fp32).
__global__ __launch_bounds__(256) void k_flash(
    const u16* __restrict__ Qd, const u16* __restrict__ Kd,
    const u16* __restrict__ Vt, u16* __restrict__ OP0, u16* __restrict__ OP1,
    float* __restrict__ Mp, float* __restrict__ Lp)
{
  __shared__ u16 Ks[64*144];
  __shared__ u16 Vs[128*72];
  __shared__ u16 Ps[4*32*72];

  const int t = threadIdx.x, lane = t & 63, wave = t >> 6;
  const int l15 = lane & 15, quad = lane >> 4;
  const int j = blockIdx.x >> 1, split = blockIdx.x & 1;
  const int h = blockIdx.y, b = blockIdx.z, bh = b*NH + h;
  const size_t base  = (size_t)bh * SEQ * HD;
  const size_t baseT = (size_t)bh * HD * SEQ;
  u16* Psw = &Ps[wave*32*72];
  u16* OPs = split ? OP1 : OP0;
  const int lo = 17*split, hi = lo + 17;
  const int qt0 = j, qt1 = 15 - j;
  const int len0 = 2*qt0 + 2;

  const int krow = t >> 4, kcol = (t & 15) * 8;
  const int vrow = t >> 3, vcol = (t & 7) * 8;

  for (int pass = 0; pass < 2; ++pass){
    const int qt = pass ? qt1 : qt0;
    const int len = 2*qt + 2;
    int kt0 = pass ? (lo - len0) : lo; if (kt0 < 0) kt0 = 0;
    int kt1 = pass ? (hi - len0) : hi; if (kt1 > len) kt1 = len;
    const int qb = qt*128 + wave*32;

    bf16x8 qf[2][4];
    #pragma unroll
    for (int mt = 0; mt < 2; ++mt)
      #pragma unroll
      for (int ks = 0; ks < 4; ++ks)
        qf[mt][ks] = *(const bf16x8*)&Qd[base + (size_t)(qb + mt*16 + l15)*HD + ks*32 + quad*8];

    f32x4 oacc[8][2] = {};
    float m_s[2] = {-1e30f, -1e30f}, l_s[2] = {0.f, 0.f};

    if (kt0 < kt1){
      uint4 kreg[4], vreg[4];
      #pragma unroll
      for (int i = 0; i < 4; ++i){
        kreg[i] = *(const uint4*)&Kd[base + (size_t)(kt0*64 + i*16 + krow)*HD + kcol];
        vreg[i] = *(const uint4*)&Vt[baseT + (size_t)(i*32 + vrow)*SEQ + kt0*64 + vcol];
      }
      for (int kt = kt0; kt < kt1; ++kt){
        __syncthreads();
        #pragma unroll
        for (int i = 0; i < 4; ++i){
          *(uint4*)&Ks[(i*16 + krow)*144 + kcol] = kreg[i];
          *(uint4*)&Vs[(i*32 + vrow)*72 + vcol] = vreg[i];
        }
        __syncthreads();
        if (kt + 1 < kt1){
          #pragma unroll
          for (int i = 0; i < 4; ++i){
            kreg[i] = *(const uint4*)&Kd[base + (size_t)((kt+1)*64 + i*16 + krow)*HD + kcol];
            vreg[i] = *(const uint4*)&Vt[baseT + (size_t)(i*32 + vrow)*SEQ + (kt+1)*64 + vcol];
          }
        }
        if (kt*64 <= qb + 31){
          f32x4 sacc[4][2] = {};
          #pragma unroll
          for (int ks = 0; ks < 4; ++ks){
            bf16x8 kf[4];
            #pragma unroll
            for (int nk = 0; nk < 4; ++nk)
              kf[nk] = *(const bf16x8*)&Ks[(nk*16 + l15)*144 + ks*32 + quad*8];
            #pragma unroll
            for (int nk = 0; nk < 4; ++nk)
              #pragma unroll
              for (int mt = 0; mt < 2; ++mt)
                sacc[nk][mt] = __builtin_amdgcn_mfma_f32_16x16x32_bf16(kf[nk], qf[mt][ks], sacc[nk][mt], 0, 0, 0);
          }
          #pragma unroll
          for (int nk = 0; nk < 4; ++nk)
            #pragma unroll
            for (int mt = 0; mt < 2; ++mt){
              int q = qb + mt*16 + l15;
              #pragma unroll
              for (int r = 0; r < 4; ++r){
                int key = kt*64 + nk*16 + quad*4 + r;
                if (key > q) sacc[nk][mt][r] = -1e30f;
              }
            }
          #pragma unroll
          for (int mt = 0; mt < 2; ++mt){
            float rm = -1e30f;
            #pragma unroll
            for (int nk = 0; nk < 4; ++nk)
              #pragma unroll
              for (int r = 0; r < 4; ++r) rm = fmaxf(rm, sacc[nk][mt][r]);
            rm = fmaxf(rm, __shfl_xor(rm, 16));
            rm = fmaxf(rm, __shfl_xor(rm, 32));
            float mnew = fmaxf(m_s[mt], rm);
            float alpha = exp2f(m_s[mt] - mnew);
            m_s[mt] = mnew;
            float rs = 0.f;
            #pragma unroll
            for (int nk = 0; nk < 4; ++nk){
              u16 pk[4];
              #pragma unroll
              for (int r = 0; r < 4; ++r){
                float p = exp2f(sacc[nk][mt][r] - mnew);
                rs += p;
                pk[r] = f2b(p);
              }
              *(uint2*)&Psw[(mt*16 + l15)*72 + nk*16 + quad*4] = *(const uint2*)pk;
            }
            rs += __shfl_xor(rs, 16);
            rs += __shfl_xor(rs, 32);
            l_s[mt] = l_s[mt]*alpha + rs;
            #pragma unroll
            for (int db = 0; db < 8; ++db)
              #pragma unroll
              for (int r = 0; r < 4; ++r) oacc[db][mt][r] *= alpha;
          }
          #pragma unroll
          for (int k2 = 0; k2 < 2; ++k2){
            bf16x8 pf[2];
            #pragma unroll
            for (int mt = 0; mt < 2; ++mt)
              pf[mt] = *(const bf16x8*)&Psw[(mt*16 + l15)*72 + k2*32 + quad*8];
            #pragma unroll
            for (int db = 0; db < 8; ++db){
              bf16x8 vf = *(const bf16x8*)&Vs[(db*16 + l15)*72 + k2*32 + quad*8];
              #pragma unroll
              for (int mt = 0; mt < 2; ++mt)
                oacc[db][mt] = __builtin_amdgcn_mfma_f32_16x16x32_bf16(vf, pf[mt], oacc[db][mt], 0, 0, 0);
            }
          }
        }
      }
    }
    // partial epilogue: unnormalized O (bf16) + m,l
    #pragma unroll
    for (int mt = 0; mt < 2; ++mt){
      int s = qb + mt*16 + l15;
      #pragma unroll
      for (int db = 0; db < 8; ++db){
        u16 ok[4];
        #pragma unroll
        for (int r = 0; r < 4; ++r) ok[r] = f2b(oacc[db][mt][r]);
        *(uint2*)&OPs[(((size_t)(b*SEQ + s))*NH + h)*HD + db*16 + quad*4] = *(const uint2*)ok;
      }
      if (quad == 0){
        size_t mi = ((size_t)split*BSZ*NH + bh)*SEQ + s;
        Mp[mi] = m_s[mt];
        Lp[mi] = l_s[mt];
      }
    }
  }
}

// ---------------------------------------------------------------- combine splits (in-place into OP0)
__global__ __launch_bounds__(256) void k_combine(
    u16* __restrict__ OP0, const u16* __restrict__ OP1,
    const float* __restrict__ Mp, const float* __restrict__ Lp)
{
  size_t flat = ((size_t)blockIdx.x*256 + threadIdx.x)*8;
  int h = (int)((flat >> 7) & 15);
  int s = (int)((flat >> 11) & 2047);
  int b = (int)(flat >> 22);
  size_t row = ((size_t)(b*NH + h))*SEQ + s;
  const size_t off1 = (size_t)BSZ*NH*SEQ;
  float m0 = Mp[row], l0 = Lp[row];
  float m1 = Mp[row + off1], l1 = Lp[row + off1];
  float m = fmaxf(m0, m1);
  float w0 = exp2f(m0 - m), w1 = exp2f(m1 - m);
  float inv = 1.0f / (w0*l0 + w1*l1);
  uint4 a = *(const uint4*)&OP0[flat];
  uint4 c = *(const uint4*)&OP1[flat];
  const u16* pa = (const u16*)&a;
  const u16* pc = (const u16*)&c;
  u16 o[8];
  #pragma unroll
  for (int i = 0; i < 8; ++i)
    o[i] = f2b((b2f(pa[i])*w0 + b2f(pc[i])*w1) * inv);
  *(uint4*)&OP0[flat] = *(const uint4*)o;
}

// ---------------------------------------------------------------- out proj
__global__ __launch_bounds__(256) void k_gemm_out(
    const u16* __restrict__ A, const u16* __restrict__ W, float* __restrict__ out)
{
  __shared__ u16 As[128*32];
  __shared__ u16 Bs[128*32];
  const int t = threadIdx.x;
  const int lane = t & 63;
  const int l15 = lane & 15, quad = lane >> 4;
  const int wave = t >> 6;
  const int wr = (wave >> 1) * 64, wc = (wave & 1) * 64;
  const int tm = blockIdx.y * 128, tn = blockIdx.x * 128;
  const int arow = t >> 2, acol = (t & 3) * 8;

  f32x4 acc[4][4] = {};
  for (int k0 = 0; k0 < DIM; k0 += 32){
    __syncthreads();
    #pragma unroll
    for (int is = 0; is < 2; ++is){
      int row = is*64 + arow;
      cp16(&As[is*2048 + t*8], &A[(size_t)(tm + row)*DIM + k0 + acol]);
      cp16(&Bs[is*2048 + t*8], &W[(size_t)(tn + row)*DIM + k0 + acol]);
    }
    __syncthreads();
    bf16x8 af[4], bfr[4];
    #pragma unroll
    for (int i = 0; i < 4; ++i){
      af[i]  = *(const bf16x8*)&As[(wr + i*16 + l15)*32 + quad*8];
      bfr[i] = *(const bf16x8*)&Bs[(wc + i*16 + l15)*32 + quad*8];
    }
    #pragma unroll
    for (int mt = 0; mt < 4; ++mt)
      #pragma unroll
      for (int nt = 0; nt < 4; ++nt)
        acc[mt][nt] = __builtin_amdgcn_mfma_f32_16x16x32_bf16(af[mt], bfr[nt], acc[mt][nt], 0, 0, 0);
  }
  #pragma unroll
  for (int mt = 0; mt < 4; ++mt)
    #pragma unroll
    for (int nt = 0; nt < 4; ++nt)
      #pragma unroll
      for (int r = 0; r < 4; ++r){
        int row = tm + wr + mt*16 + quad*4 + r;
        int col = tn + wc + nt*16 + l15;
        out[(size_t)row*DIM + col] = acc[mt][nt][r];
      }
}

// ---------------------------------------------------------------- launch
extern "C" void kernel_launch(void* const* d_in, const int* in_sizes, int n_in,
                              void* d_out, int out_size, void* d_ws, size_t ws_size,
                              hipStream_t stream)
{
  const float* x  = (const float*)d_in[0];
  const float* wq = (const float*)d_in[1];
  const float* wk = (const float*)d_in[2];
  const float* wv = (const float*)d_in[3];
  const float* wo = (const float*)d_in[4];
  const float* fc = (const float*)d_in[5];
  const float* fs = (const float*)d_in[6];
  float* out = (float*)d_out;

  char* ws = (char*)d_ws;
  u16* xb   = (u16*)(ws);                 // 16 MB  bf16 x; aliased as Vt after gemm_qkv
  u16* wqkv = (u16*)(ws + 16777216);      // 24 MB; aliased as OP1 + M/L after gemm_qkv
  u16* wob  = (u16*)(ws + 41943040);      //  8 MB
  u16* Qr   = (u16*)(ws + 50331648);      // 16 MB  (B,NH,S,HD)
  u16* Kr   = (u16*)(ws + 67108864);      // 16 MB
  u16* Vr   = (u16*)(ws + 83886080);      // 16 MB
  u16* Ob   = (u16*)(ws + 100663296);     // 16 MB  (B,S,NH,HD): split0 partial, then combined
  u16* VtT  = xb;
  u16* OP1  = wqkv;                       // 16 MB split1 partial
  float* Mp = (float*)(ws + 33554432);    // 512 KB [split][bh][s]
  float* Lp = (float*)(ws + 34078720);    // 512 KB

  k_convert <<<24576, 256, 0, stream>>>(x, wq, wk, wv, wo, xb, wqkv, wob);
  k_gemm_qkv<<<dim3(48, 32), 256, 0, stream>>>(xb, wqkv, fc, fs, Qr, Kr, Vr);
  k_vtrans  <<<dim3(32, 2, 32), 256, 0, stream>>>(Vr, VtT);
  k_flash   <<<dim3(16, NH, BSZ), 256, 0, stream>>>(Qr, Kr, VtT, Ob, OP1, Mp, Lp);
  k_combine <<<4096, 256, 0, stream>>>(Ob, OP1, Mp, Lp);
  k_gemm_out<<<dim3(16, 32), 256, 0, stream>>>(Ob, wob, out);
}

// Round 4
// 457.695 us; speedup vs baseline: 1.0689x; 1.0689x over previous
//
#include <hip/hip_runtime.h>
#include <hip/hip_bf16.h>
#include <stdint.h>

typedef __bf16 bf16x8 __attribute__((ext_vector_type(8)));
typedef float f32x4 __attribute__((ext_vector_type(4)));
typedef unsigned short u16;
typedef unsigned int u32;

#define DEVI __device__ __forceinline__

DEVI u16 f2b(float f){ __bf16 h = (__bf16)f; return __builtin_bit_cast(u16, h); }
DEVI float b2f(u16 u){ return (float)__builtin_bit_cast(__bf16, u); }

constexpr int BSZ = 2, SEQ = 2048, DIM = 2048, NH = 16, HD = 128;

#if defined(__has_builtin)
#if __has_builtin(__builtin_amdgcn_global_load_lds)
#define HAVE_ASYNC_LDS 1
#endif
#endif

DEVI void cp16(void* lds, const void* g){
#ifdef HAVE_ASYNC_LDS
  auto gp = (const __attribute__((address_space(1))) u32*)(uintptr_t)g;
  auto lp = (__attribute__((address_space(3))) u32*)(uintptr_t)lds;
  __builtin_amdgcn_global_load_lds(gp, lp, 16, 0, 0);
#else
  *(uint4*)lds = *(const uint4*)g;
#endif
}

// ---------------------------------------------------------------- convert
__global__ __launch_bounds__(256) void k_convert(
    const float* __restrict__ x, const float* __restrict__ wq,
    const float* __restrict__ wk, const float* __restrict__ wv,
    const float* __restrict__ wo,
    u16* __restrict__ xb, u16* __restrict__ wqkv, u16* __restrict__ wob)
{
  int e = (blockIdx.x * 256 + threadIdx.x) * 4;
  float4 v; u16* dp;
  if (e < 8388608){
    v = *(const float4*)&x[e]; dp = &xb[e];
  } else if (e < 20971520){
    int o = e - 8388608; int sec = o >> 22; int oo = o & 4194303;
    const float* w = (sec == 0) ? wq : ((sec == 1) ? wk : wv);
    v = *(const float4*)&w[oo]; dp = &wqkv[o];
  } else {
    int o = e - 20971520;
    v = *(const float4*)&wo[o]; dp = &wob[o];
  }
  ushort4 r; r.x = f2b(v.x); r.y = f2b(v.y); r.z = f2b(v.z); r.w = f2b(v.w);
  *(ushort4*)dp = r;
}

// ---------------------------------------------------------------- gemm QKV (+fused RoPE epilogue)
__global__ __launch_bounds__(256) void k_gemm_qkv(
    const u16* __restrict__ A, const u16* __restrict__ W,
    const float* __restrict__ fc, const float* __restrict__ fs,
    u16* __restrict__ Qd, u16* __restrict__ Kd, u16* __restrict__ Vd)
{
  __shared__ u16 As[128*32];
  __shared__ u16 Bs[128*32];
  __shared__ u16 Cs[128*136];
  const int t = threadIdx.x;
  const int lane = t & 63;
  const int l15 = lane & 15, quad = lane >> 4;
  const int wave = t >> 6;
  const int wr = (wave >> 1) * 64, wc = (wave & 1) * 64;
  const int tm = blockIdx.y * 128, tn = blockIdx.x * 128;
  const int arow = t >> 2, acol = (t & 3) * 8;

  f32x4 acc[4][4] = {};
  for (int k0 = 0; k0 < DIM; k0 += 32){
    __syncthreads();
    #pragma unroll
    for (int is = 0; is < 2; ++is){
      int row = is*64 + arow;
      cp16(&As[is*2048 + t*8], &A[(size_t)(tm + row)*DIM + k0 + acol]);
      cp16(&Bs[is*2048 + t*8], &W[(size_t)(tn + row)*DIM + k0 + acol]);
    }
    __syncthreads();
    bf16x8 af[4], bfr[4];
    #pragma unroll
    for (int i = 0; i < 4; ++i){
      af[i]  = *(const bf16x8*)&As[(wr + i*16 + l15)*32 + quad*8];
      bfr[i] = *(const bf16x8*)&Bs[(wc + i*16 + l15)*32 + quad*8];
    }
    #pragma unroll
    for (int mt = 0; mt < 4; ++mt)
      #pragma unroll
      for (int nt = 0; nt < 4; ++nt)
        acc[mt][nt] = __builtin_amdgcn_mfma_f32_16x16x32_bf16(af[mt], bfr[nt], acc[mt][nt], 0, 0, 0);
  }
  #pragma unroll
  for (int mt = 0; mt < 4; ++mt)
    #pragma unroll
    for (int nt = 0; nt < 4; ++nt)
      #pragma unroll
      for (int r = 0; r < 4; ++r)
        Cs[(wr + mt*16 + quad*4 + r)*136 + wc + nt*16 + l15] = f2b(acc[mt][nt][r]);
  __syncthreads();

  const int sec = tn >> 11;
  const int hh = (tn & 2047) >> 7;
  u16* dst = (sec == 0) ? Qd : ((sec == 1) ? Kd : Vd);
  const float qs = (sec == 0) ? (0.08838834764831845f * 1.4426950408889634f) : 1.0f;
  const int col0 = (t & 15) * 8;
  #pragma unroll
  for (int jj = 0; jj < 8; ++jj){
    int row = (t >> 4) + jj*16;
    int m = tm + row;
    int b = m >> 11, s = m & 2047;
    uint4 cv = *(const uint4*)&Cs[row*136 + col0];
    const u16* cp = (const u16*)&cv;
    u16 op[8];
    if (sec < 2){
      float4 c4 = *(const float4*)&fc[(size_t)s*64 + (col0 >> 1)];
      float4 s4 = *(const float4*)&fs[(size_t)s*64 + (col0 >> 1)];
      float cc[4] = {c4.x*qs, c4.y*qs, c4.z*qs, c4.w*qs};
      float ss[4] = {s4.x*qs, s4.y*qs, s4.z*qs, s4.w*qs};
      #pragma unroll
      for (int p = 0; p < 4; ++p){
        float a = b2f(cp[2*p]), bb = b2f(cp[2*p+1]);
        op[2*p]   = f2b(a*cc[p] - bb*ss[p]);
        op[2*p+1] = f2b(a*ss[p] + bb*cc[p]);
      }
    } else {
      #pragma unroll
      for (int p = 0; p < 8; ++p) op[p] = cp[p];
    }
    *(uint4*)&dst[((size_t)(b*NH + hh)*SEQ + s)*HD + col0] = *(const uint4*)op;
  }
}

// ---------------------------------------------------------------- V transpose
__global__ __launch_bounds__(256) void k_vtrans(
    const u16* __restrict__ V, u16* __restrict__ Vt)
{
  __shared__ u16 ts[64*72];
  const int t = threadIdx.x;
  const int st = blockIdx.x, dt = blockIdx.y, bh = blockIdx.z;
  const size_t base  = (size_t)bh * SEQ * HD;
  const size_t baseT = (size_t)bh * HD * SEQ;
  #pragma unroll
  for (int i = 0; i < 2; ++i){
    int s = i*32 + (t>>3), c = t&7;
    *(uint4*)&ts[s*72 + c*8] = *(const uint4*)&V[base + (size_t)(st*64 + s)*HD + dt*64 + c*8];
  }
  __syncthreads();
  #pragma unroll
  for (int i = 0; i < 2; ++i){
    int d = i*32 + (t>>3), sc = t&7;
    u16 tmp[8];
    #pragma unroll
    for (int j = 0; j < 8; ++j) tmp[j] = ts[(sc*8 + j)*72 + d];
    *(uint4*)&Vt[baseT + (size_t)(dt*64 + d)*SEQ + st*64 + sc*8] = *(const uint4*)tmp;
  }
}

// ---------------------------------------------------------------- flash attention
// 512 threads, 8 waves x 16 q-rows (BM=128, BN=64), split-K=2.
// grid (16, NH, B): x = j*2+split. Block's 34 stage-steps split [0,17)/[17,34).
// S^T = K.Q^T (keys in regs, queries in lanes); O^T = V^T.P^T.
__global__ __launch_bounds__(512) void k_flash(
    const u16* __restrict__ Qd, const u16* __restrict__ Kd,
    const u16* __restrict__ Vt, u16* __restrict__ OP0, u16* __restrict__ OP1,
    float* __restrict__ Mp, float* __restrict__ Lp)
{
  __shared__ u16 Ks[64*136];     // [key][d], stride 136 (2-way bank aliasing = free)
  __shared__ u16 Vs[128*72];     // [d][key], stride 72
  __shared__ u16 Ps[8*16*72];    // per-wave P [q][key], stride 72

  const int t = threadIdx.x, lane = t & 63, wave = t >> 6;
  const int l15 = lane & 15, quad = lane >> 4;
  const int j = blockIdx.x >> 1, split = blockIdx.x & 1;
  const int h = blockIdx.y, b = blockIdx.z, bh = b*NH + h;
  const size_t base  = (size_t)bh * SEQ * HD;
  const size_t baseT = (size_t)bh * HD * SEQ;
  u16* Psw = &Ps[wave*16*72];
  u16* OPs = split ? OP1 : OP0;
  const int lo = 17*split, hi = lo + 17;
  const int qt0 = j, qt1 = 15 - j;
  const int len0 = 2*qt0 + 2;

  const int krow = t >> 4, kcol = (t & 15) * 8;   // K stage: rows +i*32
  const int vrow = t >> 3, vcol = (t & 7) * 8;    // V stage: rows +i*64

  for (int pass = 0; pass < 2; ++pass){
    const int qt = pass ? qt1 : qt0;
    const int len = 2*qt + 2;
    int kt0 = pass ? (lo - len0) : lo; if (kt0 < 0) kt0 = 0;
    int kt1 = pass ? (hi - len0) : hi; if (kt1 > len) kt1 = len;
    const int qb = qt*128 + wave*16;

    bf16x8 qf[4];
    #pragma unroll
    for (int ks = 0; ks < 4; ++ks)
      qf[ks] = *(const bf16x8*)&Qd[base + (size_t)(qb + l15)*HD + ks*32 + quad*8];

    f32x4 oacc[8] = {};
    float m_s = -1e30f, l_s = 0.f;

    if (kt0 < kt1){
      uint4 kreg[2], vreg[2];
      #pragma unroll
      for (int i = 0; i < 2; ++i){
        kreg[i] = *(const uint4*)&Kd[base + (size_t)(kt0*64 + i*32 + krow)*HD + kcol];
        vreg[i] = *(const uint4*)&Vt[baseT + (size_t)(i*64 + vrow)*SEQ + kt0*64 + vcol];
      }
      for (int kt = kt0; kt < kt1; ++kt){
        __syncthreads();
        #pragma unroll
        for (int i = 0; i < 2; ++i){
          *(uint4*)&Ks[(i*32 + krow)*136 + kcol] = kreg[i];
          *(uint4*)&Vs[(i*64 + vrow)*72 + vcol] = vreg[i];
        }
        __syncthreads();
        if (kt + 1 < kt1){
          #pragma unroll
          for (int i = 0; i < 2; ++i){
            kreg[i] = *(const uint4*)&Kd[base + (size_t)((kt+1)*64 + i*32 + krow)*HD + kcol];
            vreg[i] = *(const uint4*)&Vt[baseT + (size_t)(i*64 + vrow)*SEQ + (kt+1)*64 + vcol];
          }
        }
        if (kt*64 <= qb + 15){          // wave-uniform: tile has visible keys
          f32x4 sacc[4] = {};
          #pragma unroll
          for (int ks = 0; ks < 4; ++ks){
            bf16x8 kf[4];
            #pragma unroll
            for (int nk = 0; nk < 4; ++nk)
              kf[nk] = *(const bf16x8*)&Ks[(nk*16 + l15)*136 + ks*32 + quad*8];
            #pragma unroll
            for (int nk = 0; nk < 4; ++nk)
              sacc[nk] = __builtin_amdgcn_mfma_f32_16x16x32_bf16(kf[nk], qf[ks], sacc[nk], 0, 0, 0);
          }
          if (kt*64 + 63 > qb){         // diagonal tile only: apply causal mask
            int q = qb + l15;
            #pragma unroll
            for (int nk = 0; nk < 4; ++nk)
              #pragma unroll
              for (int r = 0; r < 4; ++r){
                int key = kt*64 + nk*16 + quad*4 + r;
                if (key > q) sacc[nk][r] = -1e30f;
              }
          }
          // online softmax (tree reductions, 2 cross-quad shuffles each)
          float m4[4];
          #pragma unroll
          for (int nk = 0; nk < 4; ++nk)
            m4[nk] = fmaxf(fmaxf(sacc[nk][0], sacc[nk][1]), fmaxf(sacc[nk][2], sacc[nk][3]));
          float rm = fmaxf(fmaxf(m4[0], m4[1]), fmaxf(m4[2], m4[3]));
          rm = fmaxf(rm, __shfl_xor(rm, 16));
          rm = fmaxf(rm, __shfl_xor(rm, 32));
          float mnew = fmaxf(m_s, rm);
          float alpha = exp2f(m_s - mnew);
          m_s = mnew;
          float s4[4];
          #pragma unroll
          for (int nk = 0; nk < 4; ++nk){
            u16 pk[4];
            float p0 = exp2f(sacc[nk][0] - mnew);
            float p1 = exp2f(sacc[nk][1] - mnew);
            float p2 = exp2f(sacc[nk][2] - mnew);
            float p3 = exp2f(sacc[nk][3] - mnew);
            pk[0] = f2b(p0); pk[1] = f2b(p1); pk[2] = f2b(p2); pk[3] = f2b(p3);
            s4[nk] = (p0 + p1) + (p2 + p3);
            *(uint2*)&Psw[l15*72 + nk*16 + quad*4] = *(const uint2*)pk;
          }
          float rs = (s4[0] + s4[1]) + (s4[2] + s4[3]);
          rs += __shfl_xor(rs, 16);
          rs += __shfl_xor(rs, 32);
          l_s = l_s*alpha + rs;
          #pragma unroll
          for (int db = 0; db < 8; ++db)
            #pragma unroll
            for (int r = 0; r < 4; ++r) oacc[db][r] *= alpha;
          // O^T += V^T . P^T
          #pragma unroll
          for (int k2 = 0; k2 < 2; ++k2){
            bf16x8 pf = *(const bf16x8*)&Psw[l15*72 + k2*32 + quad*8];
            #pragma unroll
            for (int db = 0; db < 8; ++db){
              bf16x8 vf = *(const bf16x8*)&Vs[(db*16 + l15)*72 + k2*32 + quad*8];
              oacc[db] = __builtin_amdgcn_mfma_f32_16x16x32_bf16(vf, pf, oacc[db], 0, 0, 0);
            }
          }
        }
      }
    }
    // partial epilogue: unnormalized O (bf16) + m,l
    {
      int s = qb + l15;
      #pragma unroll
      for (int db = 0; db < 8; ++db){
        u16 ok[4];
        #pragma unroll
        for (int r = 0; r < 4; ++r) ok[r] = f2b(oacc[db][r]);
        *(uint2*)&OPs[(((size_t)(b*SEQ + s))*NH + h)*HD + db*16 + quad*4] = *(const uint2*)ok;
      }
      if (quad == 0){
        size_t mi = ((size_t)split*BSZ*NH + bh)*SEQ + s;
        Mp[mi] = m_s;
        Lp[mi] = l_s;
      }
    }
  }
}

// ---------------------------------------------------------------- combine splits (in-place into OP0)
__global__ __launch_bounds__(256) void k_combine(
    u16* __restrict__ OP0, const u16* __restrict__ OP1,
    const float* __restrict__ Mp, const float* __restrict__ Lp)
{
  size_t flat = ((size_t)blockIdx.x*256 + threadIdx.x)*8;
  int h = (int)((flat >> 7) & 15);
  int s = (int)((flat >> 11) & 2047);
  int b = (int)(flat >> 22);
  size_t row = ((size_t)(b*NH + h))*SEQ + s;
  const size_t off1 = (size_t)BSZ*NH*SEQ;
  float m0 = Mp[row], l0 = Lp[row];
  float m1 = Mp[row + off1], l1 = Lp[row + off1];
  float m = fmaxf(m0, m1);
  float w0 = exp2f(m0 - m), w1 = exp2f(m1 - m);
  float inv = 1.0f / (w0*l0 + w1*l1);
  uint4 a = *(const uint4*)&OP0[flat];
  uint4 c = *(const uint4*)&OP1[flat];
  const u16* pa = (const u16*)&a;
  const u16* pc = (const u16*)&c;
  u16 o[8];
  #pragma unroll
  for (int i = 0; i < 8; ++i)
    o[i] = f2b((b2f(pa[i])*w0 + b2f(pc[i])*w1) * inv);
  *(uint4*)&OP0[flat] = *(const uint4*)o;
}

// ---------------------------------------------------------------- out proj
__global__ __launch_bounds__(256) void k_gemm_out(
    const u16* __restrict__ A, const u16* __restrict__ W, float* __restrict__ out)
{
  __shared__ u16 As[128*32];
  __shared__ u16 Bs[128*32];
  const int t = threadIdx.x;
  const int lane = t & 63;
  const int l15 = lane & 15, quad = lane >> 4;
  const int wave = t >> 6;
  const int wr = (wave >> 1) * 64, wc = (wave & 1) * 64;
  const int tm = blockIdx.y * 128, tn = blockIdx.x * 128;
  const int arow = t >> 2, acol = (t & 3) * 8;

  f32x4 acc[4][4] = {};
  for (int k0 = 0; k0 < DIM; k0 += 32){
    __syncthreads();
    #pragma unroll
    for (int is = 0; is < 2; ++is){
      int row = is*64 + arow;
      cp16(&As[is*2048 + t*8], &A[(size_t)(tm + row)*DIM + k0 + acol]);
      cp16(&Bs[is*2048 + t*8], &W[(size_t)(tn + row)*DIM + k0 + acol]);
    }
    __syncthreads();
    bf16x8 af[4], bfr[4];
    #pragma unroll
    for (int i = 0; i < 4; ++i){
      af[i]  = *(const bf16x8*)&As[(wr + i*16 + l15)*32 + quad*8];
      bfr[i] = *(const bf16x8*)&Bs[(wc + i*16 + l15)*32 + quad*8];
    }
    #pragma unroll
    for (int mt = 0; mt < 4; ++mt)
      #pragma unroll
      for (int nt = 0; nt < 4; ++nt)
        acc[mt][nt] = __builtin_amdgcn_mfma_f32_16x16x32_bf16(af[mt], bfr[nt], acc[mt][nt], 0, 0, 0);
  }
  #pragma unroll
  for (int mt = 0; mt < 4; ++mt)
    #pragma unroll
    for (int nt = 0; nt < 4; ++nt)
      #pragma unroll
      for (int r = 0; r < 4; ++r){
        int row = tm + wr + mt*16 + quad*4 + r;
        int col = tn + wc + nt*16 + l15;
        out[(size_t)row*DIM + col] = acc[mt][nt][r];
      }
}

// ---------------------------------------------------------------- launch
extern "C" void kernel_launch(void* const* d_in, const int* in_sizes, int n_in,
                              void* d_out, int out_size, void* d_ws, size_t ws_size,
                              hipStream_t stream)
{
  const float* x  = (const float*)d_in[0];
  const float* wq = (const float*)d_in[1];
  const float* wk = (const float*)d_in[2];
  const float* wv = (const float*)d_in[3];
  const float* wo = (const float*)d_in[4];
  const float* fc = (const float*)d_in[5];
  const float* fs = (const float*)d_in[6];
  float* out = (float*)d_out;

  char* ws = (char*)d_ws;
  u16* xb   = (u16*)(ws);                 // 16 MB  bf16 x; aliased as Vt after gemm_qkv
  u16* wqkv = (u16*)(ws + 16777216);      // 24 MB; aliased as OP1 + M/L after gemm_qkv
  u16* wob  = (u16*)(ws + 41943040);      //  8 MB
  u16* Qr   = (u16*)(ws + 50331648);      // 16 MB  (B,NH,S,HD)
  u16* Kr   = (u16*)(ws + 67108864);      // 16 MB
  u16* Vr   = (u16*)(ws + 83886080);      // 16 MB
  u16* Ob   = (u16*)(ws + 100663296);     // 16 MB  (B,S,NH,HD): split0 partial, then combined
  u16* VtT  = xb;
  u16* OP1  = wqkv;                       // 16 MB split1 partial
  float* Mp = (float*)(ws + 33554432);    // 512 KB [split][bh][s]
  float* Lp = (float*)(ws + 34078720);    // 512 KB

  k_convert <<<24576, 256, 0, stream>>>(x, wq, wk, wv, wo, xb, wqkv, wob);
  k_gemm_qkv<<<dim3(48, 32), 256, 0, stream>>>(xb, wqkv, fc, fs, Qr, Kr, Vr);
  k_vtrans  <<<dim3(32, 2, 32), 256, 0, stream>>>(Vr, VtT);
  k_flash   <<<dim3(16, NH, BSZ), 512, 0, stream>>>(Qr, Kr, VtT, Ob, OP1, Mp, Lp);
  k_combine <<<4096, 256, 0, stream>>>(Ob, OP1, Mp, Lp);
  k_gemm_out<<<dim3(16, 32), 256, 0, stream>>>(Ob, wob, out);
}